// Round 14
// baseline (154.057 us; speedup 1.0000x reference)
//
#include <hip/hip_runtime.h>

#define N_NODES 100000
#define N_EDGES 1600000
#define IN_DIM  64
#define HID     128
#define BN_EPS  1e-5f

// two-level counting sort geometry (128-node buckets)
#define NB        782      // coarse buckets: dst>>7
#define BC_BLOCKS 196      // binning blocks, 8192 edges each
#define EPB4      2048     // int4s per binning block
#define SC_PAD    153600   // NB*BC_BLOCKS=153272 padded
#define SC_NBLK   150
#define CONV_BLOCKS 6250   // N_NODES*IN_DIM/4 / 256 exactly

// syrk geometry
#define SYRK_BLOCKS 256
#define SYRK_ROWS   391    // 256*391 >= N_NODES
#define GSZ         4160   // 64*64 G + 64 colsum

#define SRC_MASK  0x1FFFF  // 17 bits (N_NODES < 2^17)
#define LDS_CAP_H 1536     // max edges per HALF-bucket in LDS (mean 1024, +22 sigma)

// ---------------- 1. fat kernel: binCount + h->bf16 + pad-tail zero ----------------
__device__ __forceinline__ unsigned bf16rne(float f) {
    unsigned b = __float_as_uint(f);
    return (b + 0x7FFFu + ((b >> 16) & 1u)) >> 16;
}

__global__ __launch_bounds__(256) void count_conv_kernel(
    const int* __restrict__ dst, int* __restrict__ counts,
    const float* __restrict__ h, unsigned short* __restrict__ h16)
{
    __shared__ int hist[NB];
    const int t = threadIdx.x;
    if (blockIdx.x < BC_BLOCKS) {
        const int blk = blockIdx.x;
        for (int i = t; i < NB; i += 256) hist[i] = 0;
        __syncthreads();
        const int4* d4 = (const int4*)dst;
        const int base = blk * EPB4;
#pragma unroll
        for (int it = 0; it < 8; ++it) {
            int i = base + it * 256 + t;
            if (i < N_EDGES / 4) {
                int4 v = d4[i];
                atomicAdd(&hist[v.x >> 7], 1);
                atomicAdd(&hist[v.y >> 7], 1);
                atomicAdd(&hist[v.z >> 7], 1);
                atomicAdd(&hist[v.w >> 7], 1);
            }
        }
        __syncthreads();
        for (int i = t; i < NB; i += 256) counts[i * BC_BLOCKS + blk] = hist[i];
    } else if (blockIdx.x < BC_BLOCKS + CONV_BLOCKS) {
        int i = (blockIdx.x - BC_BLOCKS) * 256 + t;
        if (i < N_NODES * IN_DIM / 4) {
            float4 v = ((const float4*)h)[i];
            uint2 o;
            o.x = bf16rne(v.x) | (bf16rne(v.y) << 16);
            o.y = bf16rne(v.z) | (bf16rne(v.w) << 16);
            ((uint2*)h16)[i] = o;
        }
    } else {
        // zero the scan pad tail (replaces a rocclr fill dispatch)
        for (int i = NB * BC_BLOCKS + t; i < SC_PAD; i += 256) counts[i] = 0;
    }
}

// ---------------- 2. hierarchical exclusive scan of counts ----------------
__global__ __launch_bounds__(256) void scanA_kernel(const int* __restrict__ counts,
                                                    int* __restrict__ blockSums)
{
    __shared__ int lds[256];
    int t = threadIdx.x;
    int4 v = ((const int4*)counts)[blockIdx.x * 256 + t];
    lds[t] = v.x + v.y + v.z + v.w;
    __syncthreads();
    for (int off = 128; off > 0; off >>= 1) {
        if (t < off) lds[t] += lds[t + off];
        __syncthreads();
    }
    if (t == 0) blockSums[blockIdx.x] = lds[0];
}

__global__ __launch_bounds__(256) void scanB_kernel(const int* __restrict__ blockSums,
                                                    int* __restrict__ blockOff)
{
    __shared__ int lds[256];
    int t = threadIdx.x;
    int v = (t < SC_NBLK) ? blockSums[t] : 0;
    lds[t] = v;
    __syncthreads();
    for (int off = 1; off < 256; off <<= 1) {
        int u = (t >= off) ? lds[t - off] : 0;
        __syncthreads();
        lds[t] += u;
        __syncthreads();
    }
    if (t < SC_NBLK) blockOff[t] = lds[t] - v;
}

__global__ __launch_bounds__(256) void scanC_kernel(const int* __restrict__ counts,
                                                    const int* __restrict__ blockOff,
                                                    int* __restrict__ scanned)
{
    __shared__ int lds[256];
    int t = threadIdx.x;
    int idx = blockIdx.x * 256 + t;
    int4 v = ((const int4*)counts)[idx];
    int tsum = v.x + v.y + v.z + v.w;
    lds[t] = tsum;
    __syncthreads();
    for (int off = 1; off < 256; off <<= 1) {
        int u = (t >= off) ? lds[t - off] : 0;
        __syncthreads();
        lds[t] += u;
        __syncthreads();
    }
    int base = blockOff[blockIdx.x] + lds[t] - tsum;
    int i0 = idx * 4;
    scanned[i0 + 0] = base;
    scanned[i0 + 1] = base + v.x;
    scanned[i0 + 2] = base + v.x + v.y;
    scanned[i0 + 3] = base + v.x + v.y + v.z;
}

// ---------------- 3. place packed (dstLocal<<17|src) into coarse buckets ----------------
__global__ __launch_bounds__(256) void binPlace_kernel(const int* __restrict__ src,
                                                       const int* __restrict__ dst,
                                                       const int* __restrict__ scanned,
                                                       int* __restrict__ packed)
{
    __shared__ int cur[NB];
    const int t = threadIdx.x, blk = blockIdx.x;
    for (int i = t; i < NB; i += 256) cur[i] = scanned[i * BC_BLOCKS + blk];
    __syncthreads();
    const int4* d4 = (const int4*)dst;
    const int4* s4 = (const int4*)src;
    const int base = blk * EPB4;
#pragma unroll
    for (int it = 0; it < 8; ++it) {
        int i = base + it * 256 + t;
        if (i < N_EDGES / 4) {
            int4 dv = d4[i];
            int4 sv = s4[i];
            int p0 = atomicAdd(&cur[dv.x >> 7], 1);
            packed[p0] = ((dv.x & 127) << 17) | sv.x;
            int p1 = atomicAdd(&cur[dv.y >> 7], 1);
            packed[p1] = ((dv.y & 127) << 17) | sv.y;
            int p2 = atomicAdd(&cur[dv.z >> 7], 1);
            packed[p2] = ((dv.z & 127) << 17) | sv.z;
            int p3 = atomicAdd(&cur[dv.w >> 7], 1);
            packed[p3] = ((dv.w & 127) << 17) | sv.w;
        }
    }
}

// ---------------- 4. half-bucket in-LDS sort + quad-lane bf16 gather ----------------
// TWO blocks per 128-node bucket (grid 2*NB, 256 threads = 4 waves each).
// block handles bucket b>>1, half b&1 (nodes with dstLocal bit6 == half).
// lane p in [0,16) owns features 4p..4p+3 (one uint2 of h16);
// side = lane>>4 in [0,4) takes every 4th edge; shfl_xor(16)+(32) combines.
__global__ __launch_bounds__(256) void sortAgg_kernel(
    const uint2* __restrict__ h16v, const int* __restrict__ packed,
    const int* __restrict__ scanned, float* __restrict__ agg)
{
    __shared__ int edges[LDS_CAP_H];
    __shared__ int hist[64], scn[64], cur[64], offs[65];
    const int b = blockIdx.x >> 1, half = blockIdx.x & 1;
    const int t = threadIdx.x;
    const int beg = scanned[b * BC_BLOCKS];
    const int end = scanned[(b + 1) * BC_BLOCKS];
    const int n = end - beg;

    if (t < 64) hist[t] = 0;
    __syncthreads();
    for (int i = t; i < n; i += 256) {
        int loc = packed[beg + i] >> 17;
        if ((loc >> 6) == half) atomicAdd(&hist[loc & 63], 1);
    }
    __syncthreads();
    int v = (t < 64) ? hist[t] : 0;
    if (t < 64) scn[t] = v;
    __syncthreads();
    for (int off = 1; off < 64; off <<= 1) {
        int u = (t < 64 && t >= off) ? scn[t - off] : 0;
        __syncthreads();
        if (t < 64) scn[t] += u;
        __syncthreads();
    }
    if (t < 64) { offs[t] = scn[t] - v; cur[t] = scn[t] - v; }
    if (t == 63) offs[64] = scn[63];   // n_half
    __syncthreads();
    const int nh = offs[64];
    const bool fast = (nh <= LDS_CAP_H);
    if (fast) {
        for (int i = t; i < n; i += 256) {
            int pk = packed[beg + i];
            int loc = pk >> 17;
            if ((loc >> 6) == half) {
                int pos = atomicAdd(&cur[loc & 63], 1);
                edges[pos] = pk & SRC_MASK;
            }
        }
    }
    __syncthreads();

    const int lane = t & 63, w = t >> 6;     // 4 waves
    const int p = lane & 15;                 // feature quad: 4p..4p+3
    const int side = lane >> 4;              // 0..3 within wave
    const int node0 = (b << 7) + (half << 6);

    for (int ln = w; ln < 64; ln += 4) {
        int node = node0 + ln;
        if (node >= N_NODES) break;  // ln monotone per wave
        float4 acc = make_float4(0.f, 0.f, 0.f, 0.f);
        if (fast) {
            const int o0 = offs[ln];
            const int cnt = offs[ln + 1] - o0;
            int j = side;
            for (; j + 12 < cnt; j += 16) {
                int s0 = edges[o0 + j];
                int s1 = edges[o0 + j + 4];
                int s2 = edges[o0 + j + 8];
                int s3 = edges[o0 + j + 12];
                uint2 u0 = h16v[s0 * 16 + p];
                uint2 u1 = h16v[s1 * 16 + p];
                uint2 u2 = h16v[s2 * 16 + p];
                uint2 u3 = h16v[s3 * 16 + p];
                acc.x += __uint_as_float(u0.x << 16);
                acc.y += __uint_as_float(u0.x & 0xFFFF0000u);
                acc.z += __uint_as_float(u0.y << 16);
                acc.w += __uint_as_float(u0.y & 0xFFFF0000u);
                acc.x += __uint_as_float(u1.x << 16);
                acc.y += __uint_as_float(u1.x & 0xFFFF0000u);
                acc.z += __uint_as_float(u1.y << 16);
                acc.w += __uint_as_float(u1.y & 0xFFFF0000u);
                acc.x += __uint_as_float(u2.x << 16);
                acc.y += __uint_as_float(u2.x & 0xFFFF0000u);
                acc.z += __uint_as_float(u2.y << 16);
                acc.w += __uint_as_float(u2.y & 0xFFFF0000u);
                acc.x += __uint_as_float(u3.x << 16);
                acc.y += __uint_as_float(u3.x & 0xFFFF0000u);
                acc.z += __uint_as_float(u3.y << 16);
                acc.w += __uint_as_float(u3.y & 0xFFFF0000u);
            }
            for (; j < cnt; j += 4) {
                uint2 u = h16v[edges[o0 + j] * 16 + p];
                acc.x += __uint_as_float(u.x << 16);
                acc.y += __uint_as_float(u.x & 0xFFFF0000u);
                acc.z += __uint_as_float(u.y << 16);
                acc.w += __uint_as_float(u.y & 0xFFFF0000u);
            }
        } else {
            // overflow fallback (statistically unreachable): filter-scan the run
            const int want = (half << 6) | ln;
            for (int i = side; i < n; i += 4) {
                int pk = packed[beg + i];
                if ((pk >> 17) == want) {
                    uint2 u = h16v[(pk & SRC_MASK) * 16 + p];
                    acc.x += __uint_as_float(u.x << 16);
                    acc.y += __uint_as_float(u.x & 0xFFFF0000u);
                    acc.z += __uint_as_float(u.y << 16);
                    acc.w += __uint_as_float(u.y & 0xFFFF0000u);
                }
            }
        }
        acc.x += __shfl_xor(acc.x, 16);
        acc.y += __shfl_xor(acc.y, 16);
        acc.z += __shfl_xor(acc.z, 16);
        acc.w += __shfl_xor(acc.w, 16);
        acc.x += __shfl_xor(acc.x, 32);
        acc.y += __shfl_xor(acc.y, 32);
        acc.z += __shfl_xor(acc.z, 32);
        acc.w += __shfl_xor(acc.w, 32);
        if (side == 0)
            ((float4*)(agg + (size_t)node * IN_DIM))[p] = acc;
    }
}

// ---------------- 5. syrk: G-partials = agg^T agg, colsum partials ----------------
__global__ __launch_bounds__(256) void syrk_kernel(const float* __restrict__ agg,
                                                   float* __restrict__ Gp)
{
    __shared__ float As[32][64];
    const int t = threadIdx.x, blk = blockIdx.x;
    const int row_beg = blk * SYRK_ROWS;
    int row_end = row_beg + SYRK_ROWS;
    if (row_end > N_NODES) row_end = N_NODES;

    const int i0 = (t & 15) * 4, j0 = (t >> 4) * 4;
    float acc[4][4];
#pragma unroll
    for (int i = 0; i < 4; i++)
#pragma unroll
        for (int j = 0; j < 4; j++) acc[i][j] = 0.f;
    float cs = 0.f;

    for (int r0 = row_beg; r0 < row_end; r0 += 32) {
        int nrows = row_end - r0; if (nrows > 32) nrows = 32;
        for (int i = t; i < nrows * 16; i += 256)
            ((float4*)&As[0][0])[i] = ((const float4*)(agg + (size_t)r0 * IN_DIM))[i];
        __syncthreads();
        for (int r = 0; r < nrows; ++r) {
            float4 ai = *(const float4*)&As[r][i0];
            float4 aj = *(const float4*)&As[r][j0];
            acc[0][0] += ai.x * aj.x; acc[0][1] += ai.x * aj.y;
            acc[0][2] += ai.x * aj.z; acc[0][3] += ai.x * aj.w;
            acc[1][0] += ai.y * aj.x; acc[1][1] += ai.y * aj.y;
            acc[1][2] += ai.y * aj.z; acc[1][3] += ai.y * aj.w;
            acc[2][0] += ai.z * aj.x; acc[2][1] += ai.z * aj.y;
            acc[2][2] += ai.z * aj.z; acc[2][3] += ai.z * aj.w;
            acc[3][0] += ai.w * aj.x; acc[3][1] += ai.w * aj.y;
            acc[3][2] += ai.w * aj.z; acc[3][3] += ai.w * aj.w;
        }
        if (t < 64) {
            for (int r = 0; r < nrows; ++r) cs += As[r][t];
        }
        __syncthreads();
    }
    float* gp = Gp + (size_t)blk * GSZ;
#pragma unroll
    for (int i = 0; i < 4; i++)
#pragma unroll
        for (int j = 0; j < 4; j++)
            gp[(i0 + i) * 64 + (j0 + j)] = acc[i][j];
    if (t < 64) gp[4096 + t] = cs;
}

// ---------------- 6. reduce G partials ----------------
__global__ __launch_bounds__(256) void reduceG_kernel(const float* __restrict__ Gp,
                                                      float* __restrict__ G)
{
    int gid = blockIdx.x * 256 + threadIdx.x;
    if (gid < GSZ) {
        float s = 0.f;
        for (int b = 0; b < SYRK_BLOCKS; ++b) s += Gp[(size_t)b * GSZ + gid];
        G[gid] = s;
    }
}

// ---------------- 7. finalize: per-column scale/shift from G ----------------
__global__ __launch_bounds__(256) void finalize_kernel(
    const float* __restrict__ G, const float* __restrict__ W,
    const float* __restrict__ bias, const float* __restrict__ gamma,
    const float* __restrict__ beta, float* __restrict__ scale,
    float* __restrict__ shift)
{
    __shared__ float Gs[4096];
    __shared__ float ss[64];
    __shared__ float part[256];
    const int t = threadIdx.x;
    for (int i = t; i < 4096; i += 256) Gs[i] = G[i];
    if (t < 64) ss[t] = G[4096 + t];
    __syncthreads();

    const int c = t & 127, half = t >> 7;
    float wc[64];
#pragma unroll
    for (int k = 0; k < 64; ++k) wc[k] = W[k * HID + c];

    float p = 0.f;
    for (int k1 = 0; k1 < 32; ++k1) {
        int k1g = half * 32 + k1;
        float dot = 0.f;
#pragma unroll
        for (int k2 = 0; k2 < 64; ++k2) dot += Gs[k1g * 64 + k2] * wc[k2];
        p += W[k1g * HID + c] * dot;
    }
    part[t] = p;
    __syncthreads();
    if (half == 0) {
        float quad = part[c] + part[c + 128];  // w_c^T G w_c
        float tc = 0.f;
#pragma unroll
        for (int k = 0; k < 64; ++k) tc += ss[k] * wc[k];
        const float invN = 1.0f / (float)N_NODES;
        float bc   = bias[c];
        float mean = tc * invN + bc;
        float ez2  = quad * invN + 2.f * bc * tc * invN + bc * bc;
        float var  = ez2 - mean * mean;
        float inv  = rsqrtf(var + BN_EPS);
        float scv  = gamma[c] * inv;
        scale[c] = scv;
        shift[c] = beta[c] - mean * scv;
    }
}

// ---------------- 8. GEMM + scale/shift: LDS W + transposed-A, 4x4 per thread ----------------
#define AST_LD 36   // row stride of Ast in floats (144 B: 16B-aligned, odd bank group)
__global__ __launch_bounds__(256) void gemm_out_kernel(
    const float* __restrict__ agg, const float* __restrict__ W,
    const float* __restrict__ scale, const float* __restrict__ shift,
    float* __restrict__ out)
{
    __shared__ float Ws[IN_DIM][HID];        // 32 KB
    __shared__ float Ast[IN_DIM][AST_LD];    // 9 KB, Ast[k][row]
    const int t = threadIdx.x;
    const int tile = blockIdx.x;
    const int rowbase = tile * 32;

    {
        const float4* s4 = (const float4*)W;
        float4* d4 = (float4*)&Ws[0][0];
#pragma unroll
        for (int i = 0; i < (IN_DIM * HID / 4) / 256; ++i)
            d4[t + i * 256] = s4[t + i * 256];
    }
    {
        const float4* s4 = (const float4*)(agg + (size_t)rowbase * IN_DIM);
#pragma unroll
        for (int it = 0; it < 2; ++it) {
            int l = t + it * 256;
            float4 a = s4[l];
            int row = l >> 4, kg = (l & 15) * 4;
            Ast[kg + 0][row] = a.x;
            Ast[kg + 1][row] = a.y;
            Ast[kg + 2][row] = a.z;
            Ast[kg + 3][row] = a.w;
        }
    }
    __syncthreads();

    const int c4 = (t & 31) * 4;
    const int r0 = (t >> 5) * 4;

    float acc[4][4];
#pragma unroll
    for (int i = 0; i < 4; i++)
#pragma unroll
        for (int j = 0; j < 4; j++) acc[i][j] = 0.f;

#pragma unroll 8
    for (int k = 0; k < IN_DIM; ++k) {
        float4 w4 = *(const float4*)&Ws[k][c4];
        float4 a4 = *(const float4*)&Ast[k][r0];
        acc[0][0] += a4.x * w4.x; acc[0][1] += a4.x * w4.y;
        acc[0][2] += a4.x * w4.z; acc[0][3] += a4.x * w4.w;
        acc[1][0] += a4.y * w4.x; acc[1][1] += a4.y * w4.y;
        acc[1][2] += a4.y * w4.z; acc[1][3] += a4.y * w4.w;
        acc[2][0] += a4.z * w4.x; acc[2][1] += a4.z * w4.y;
        acc[2][2] += a4.z * w4.z; acc[2][3] += a4.z * w4.w;
        acc[3][0] += a4.w * w4.x; acc[3][1] += a4.w * w4.y;
        acc[3][2] += a4.w * w4.z; acc[3][3] += a4.w * w4.w;
    }

    const float4 sc4 = ((const float4*)scale)[t & 31];
    const float4 sh4 = ((const float4*)shift)[t & 31];
#pragma unroll
    for (int i = 0; i < 4; ++i) {
        float4 o;
        o.x = acc[i][0] * sc4.x + sh4.x;
        o.y = acc[i][1] * sc4.y + sh4.y;
        o.z = acc[i][2] * sc4.z + sh4.z;
        o.w = acc[i][3] * sc4.w + sh4.w;
        *(float4*)&out[(size_t)(rowbase + r0 + i) * HID + c4] = o;
    }
}

extern "C" void kernel_launch(void* const* d_in, const int* in_sizes, int n_in,
                              void* d_out, int out_size, void* d_ws, size_t ws_size,
                              hipStream_t stream)
{
    const float* h     = (const float*)d_in[0];
    const int*   src   = (const int*)d_in[1];
    const int*   dst   = (const int*)d_in[2];
    const float* W     = (const float*)d_in[3];
    const float* b     = (const float*)d_in[4];
    const float* gamma = (const float*)d_in[5];
    const float* beta  = (const float*)d_in[6];

    float* out = (float*)d_out;

    // ---- workspace layout ----
    float* agg  = (float*)d_ws;
    unsigned short* h16 = (unsigned short*)(agg + (size_t)N_NODES * IN_DIM);
    float* G     = (float*)(h16 + (size_t)N_NODES * IN_DIM);
    float* scale = G + GSZ;
    float* shift = scale + HID;
    int*  counts    = (int*)(shift + HID);
    int*  blockSums = counts + SC_PAD;
    int*  blockOff  = blockSums + 256;
    int*  scanned   = blockOff + 256;
    int*  packed    = scanned + SC_PAD;          // N_EDGES ints
    float* Gp       = (float*)counts;            // aliases sort transients (dead by syrk)

    count_conv_kernel<<<BC_BLOCKS + CONV_BLOCKS + 1, 256, 0, stream>>>(dst, counts,
                                                                       h, h16);
    scanA_kernel<<<SC_NBLK, 256, 0, stream>>>(counts, blockSums);
    scanB_kernel<<<1, 256, 0, stream>>>(blockSums, blockOff);
    scanC_kernel<<<SC_NBLK, 256, 0, stream>>>(counts, blockOff, scanned);
    binPlace_kernel<<<BC_BLOCKS, 256, 0, stream>>>(src, dst, scanned, packed);
    sortAgg_kernel<<<NB * 2, 256, 0, stream>>>((const uint2*)h16, packed, scanned, agg);
    syrk_kernel<<<SYRK_BLOCKS, 256, 0, stream>>>(agg, Gp);
    reduceG_kernel<<<(GSZ + 255) / 256, 256, 0, stream>>>(Gp, G);
    finalize_kernel<<<1, 256, 0, stream>>>(G, W, b, gamma, beta, scale, shift);
    gemm_out_kernel<<<N_NODES / 32, 256, 0, stream>>>(agg, W, scale, shift, out);
}

// Round 15
// 152.570 us; speedup vs baseline: 1.0097x; 1.0097x over previous
//
#include <hip/hip_runtime.h>

#define N_NODES 100000
#define N_EDGES 1600000
#define IN_DIM  64
#define HID     128
#define BN_EPS  1e-5f

// two-level counting sort geometry (128-node buckets)
#define NB        782      // coarse buckets: dst>>7
#define BC_BLOCKS 196      // binning blocks, 8192 edges each
#define EPB4      2048     // int4s per binning block
#define SC_PAD    153600   // NB*BC_BLOCKS=153272 padded
#define SC_NBLK   150
#define CONV_BLOCKS 6250   // N_NODES*IN_DIM/4 / 256 exactly

// syrk geometry
#define SYRK_BLOCKS 256
#define SYRK_ROWS   391    // 256*391 >= N_NODES
#define GSZ         4160   // 64*64 G + 64 colsum

#define SRC_MASK  0x1FFFF  // 17 bits (N_NODES < 2^17)
#define LDS_CAP   3072     // max edges per bucket staged in LDS (mean 2048, sigma 45)

__device__ __forceinline__ unsigned bf16rne(float f) {
    unsigned b = __float_as_uint(f);
    return (b + 0x7FFFu + ((b >> 16) & 1u)) >> 16;
}
__device__ __forceinline__ float bf16lo(unsigned u) { return __uint_as_float(u << 16); }
__device__ __forceinline__ float bf16hi(unsigned u) { return __uint_as_float(u & 0xFFFF0000u); }

// ---------------- 1. fat kernel: binCount + h->bf16 + pad-tail zero ----------------
__global__ __launch_bounds__(256) void count_conv_kernel(
    const int* __restrict__ dst, int* __restrict__ counts,
    const float* __restrict__ h, unsigned short* __restrict__ h16)
{
    __shared__ int hist[NB];
    const int t = threadIdx.x;
    if (blockIdx.x < BC_BLOCKS) {
        const int blk = blockIdx.x;
        for (int i = t; i < NB; i += 256) hist[i] = 0;
        __syncthreads();
        const int4* d4 = (const int4*)dst;
        const int base = blk * EPB4;
#pragma unroll
        for (int it = 0; it < 8; ++it) {
            int i = base + it * 256 + t;
            if (i < N_EDGES / 4) {
                int4 v = d4[i];
                atomicAdd(&hist[v.x >> 7], 1);
                atomicAdd(&hist[v.y >> 7], 1);
                atomicAdd(&hist[v.z >> 7], 1);
                atomicAdd(&hist[v.w >> 7], 1);
            }
        }
        __syncthreads();
        for (int i = t; i < NB; i += 256) counts[i * BC_BLOCKS + blk] = hist[i];
    } else if (blockIdx.x < BC_BLOCKS + CONV_BLOCKS) {
        int i = (blockIdx.x - BC_BLOCKS) * 256 + t;
        if (i < N_NODES * IN_DIM / 4) {
            float4 v = ((const float4*)h)[i];
            uint2 o;
            o.x = bf16rne(v.x) | (bf16rne(v.y) << 16);
            o.y = bf16rne(v.z) | (bf16rne(v.w) << 16);
            ((uint2*)h16)[i] = o;
        }
    } else {
        for (int i = NB * BC_BLOCKS + t; i < SC_PAD; i += 256) counts[i] = 0;
    }
}

// ---------------- 2a. per-block sums ----------------
__global__ __launch_bounds__(256) void scanA_kernel(const int* __restrict__ counts,
                                                    int* __restrict__ blockSums)
{
    __shared__ int lds[256];
    int t = threadIdx.x;
    int4 v = ((const int4*)counts)[blockIdx.x * 256 + t];
    lds[t] = v.x + v.y + v.z + v.w;
    __syncthreads();
    for (int off = 128; off > 0; off >>= 1) {
        if (t < off) lds[t] += lds[t + off];
        __syncthreads();
    }
    if (t == 0) blockSums[blockIdx.x] = lds[0];
}

// ---------------- 2b. scanC with fused block-offset scan (scanB folded in) ----------------
__global__ __launch_bounds__(256) void scanC_kernel(const int* __restrict__ counts,
                                                    const int* __restrict__ blockSums,
                                                    int* __restrict__ scanned)
{
    __shared__ int bsum[256];
    __shared__ int lds[256];
    int t = threadIdx.x;
    // redundant scan of the 150 block sums in every block (cheap, saves a launch)
    int bv = (t < SC_NBLK) ? blockSums[t] : 0;
    bsum[t] = bv;
    __syncthreads();
    for (int off = 1; off < 256; off <<= 1) {
        int u = (t >= off) ? bsum[t - off] : 0;
        __syncthreads();
        bsum[t] += u;
        __syncthreads();
    }
    const int blockOff = bsum[blockIdx.x] - blockSums[blockIdx.x];  // exclusive

    int idx = blockIdx.x * 256 + t;
    int4 v = ((const int4*)counts)[idx];
    int tsum = v.x + v.y + v.z + v.w;
    lds[t] = tsum;
    __syncthreads();
    for (int off = 1; off < 256; off <<= 1) {
        int u = (t >= off) ? lds[t - off] : 0;
        __syncthreads();
        lds[t] += u;
        __syncthreads();
    }
    int base = blockOff + lds[t] - tsum;
    int i0 = idx * 4;
    scanned[i0 + 0] = base;
    scanned[i0 + 1] = base + v.x;
    scanned[i0 + 2] = base + v.x + v.y;
    scanned[i0 + 3] = base + v.x + v.y + v.z;
}

// ---------------- 3. place packed (dstLocal<<17|src) into coarse buckets ----------------
__global__ __launch_bounds__(256) void binPlace_kernel(const int* __restrict__ src,
                                                       const int* __restrict__ dst,
                                                       const int* __restrict__ scanned,
                                                       int* __restrict__ packed)
{
    __shared__ int cur[NB];
    const int t = threadIdx.x, blk = blockIdx.x;
    for (int i = t; i < NB; i += 256) cur[i] = scanned[i * BC_BLOCKS + blk];
    __syncthreads();
    const int4* d4 = (const int4*)dst;
    const int4* s4 = (const int4*)src;
    const int base = blk * EPB4;
#pragma unroll
    for (int it = 0; it < 8; ++it) {
        int i = base + it * 256 + t;
        if (i < N_EDGES / 4) {
            int4 dv = d4[i];
            int4 sv = s4[i];
            int p0 = atomicAdd(&cur[dv.x >> 7], 1);
            packed[p0] = ((dv.x & 127) << 17) | sv.x;
            int p1 = atomicAdd(&cur[dv.y >> 7], 1);
            packed[p1] = ((dv.y & 127) << 17) | sv.y;
            int p2 = atomicAdd(&cur[dv.z >> 7], 1);
            packed[p2] = ((dv.z & 127) << 17) | sv.z;
            int p3 = atomicAdd(&cur[dv.w >> 7], 1);
            packed[p3] = ((dv.w & 127) << 17) | sv.w;
        }
    }
}

// ---------------- 4. fused in-LDS node sort + quad-lane bf16 gather, bf16 agg out ----------------
// one block per 128-node bucket, 512 threads = 8 waves (round-13 proven shape).
// lane p in [0,16) owns features 4p..4p+3; side = lane>>4 takes every 4th edge.
__global__ __launch_bounds__(512) void sortAgg_kernel(
    const uint2* __restrict__ h16v, const int* __restrict__ packed,
    const int* __restrict__ scanned, unsigned short* __restrict__ agg16)
{
    __shared__ int edges[LDS_CAP];
    __shared__ int hist[128], scn[128], cur[128], offs[129];
    const int b = blockIdx.x, t = threadIdx.x;
    const int beg = scanned[b * BC_BLOCKS];
    const int end = scanned[(b + 1) * BC_BLOCKS];
    const int n = end - beg;

    if (t < 128) hist[t] = 0;
    __syncthreads();
    for (int i = t; i < n; i += 512)
        atomicAdd(&hist[packed[beg + i] >> 17], 1);
    __syncthreads();
    int v = (t < 128) ? hist[t] : 0;
    if (t < 128) scn[t] = v;
    __syncthreads();
    for (int off = 1; off < 128; off <<= 1) {
        int u = (t < 128 && t >= off) ? scn[t - off] : 0;
        __syncthreads();
        if (t < 128) scn[t] += u;
        __syncthreads();
    }
    if (t < 128) { offs[t] = scn[t] - v; cur[t] = scn[t] - v; }
    if (t == 0) offs[128] = n;
    __syncthreads();
    const bool fast = (n <= LDS_CAP);
    if (fast) {
        for (int i = t; i < n; i += 512) {
            int p = packed[beg + i];
            int pos = atomicAdd(&cur[p >> 17], 1);
            edges[pos] = p & SRC_MASK;
        }
    }
    __syncthreads();

    const int lane = t & 63, w = t >> 6;
    const int p = lane & 15;        // feature quad: 4p..4p+3
    const int side = lane >> 4;     // 0..3 within wave
    const int node0 = b << 7;

    for (int ln = w; ln < 128; ln += 8) {
        int node = node0 + ln;
        if (node >= N_NODES) break;
        float4 acc = make_float4(0.f, 0.f, 0.f, 0.f);
        if (fast) {
            const int o0 = offs[ln];
            const int cnt = offs[ln + 1] - o0;
            int j = side;
            for (; j + 12 < cnt; j += 16) {
                int s0 = edges[o0 + j];
                int s1 = edges[o0 + j + 4];
                int s2 = edges[o0 + j + 8];
                int s3 = edges[o0 + j + 12];
                uint2 u0 = h16v[s0 * 16 + p];
                uint2 u1 = h16v[s1 * 16 + p];
                uint2 u2 = h16v[s2 * 16 + p];
                uint2 u3 = h16v[s3 * 16 + p];
                acc.x += bf16lo(u0.x); acc.y += bf16hi(u0.x);
                acc.z += bf16lo(u0.y); acc.w += bf16hi(u0.y);
                acc.x += bf16lo(u1.x); acc.y += bf16hi(u1.x);
                acc.z += bf16lo(u1.y); acc.w += bf16hi(u1.y);
                acc.x += bf16lo(u2.x); acc.y += bf16hi(u2.x);
                acc.z += bf16lo(u2.y); acc.w += bf16hi(u2.y);
                acc.x += bf16lo(u3.x); acc.y += bf16hi(u3.x);
                acc.z += bf16lo(u3.y); acc.w += bf16hi(u3.y);
            }
            for (; j < cnt; j += 4) {
                uint2 u = h16v[edges[o0 + j] * 16 + p];
                acc.x += bf16lo(u.x); acc.y += bf16hi(u.x);
                acc.z += bf16lo(u.y); acc.w += bf16hi(u.y);
            }
        } else {
            for (int i = side; i < n; i += 4) {
                int pk = packed[beg + i];
                if ((pk >> 17) == ln) {
                    uint2 u = h16v[(pk & SRC_MASK) * 16 + p];
                    acc.x += bf16lo(u.x); acc.y += bf16hi(u.x);
                    acc.z += bf16lo(u.y); acc.w += bf16hi(u.y);
                }
            }
        }
        acc.x += __shfl_xor(acc.x, 16);
        acc.y += __shfl_xor(acc.y, 16);
        acc.z += __shfl_xor(acc.z, 16);
        acc.w += __shfl_xor(acc.w, 16);
        acc.x += __shfl_xor(acc.x, 32);
        acc.y += __shfl_xor(acc.y, 32);
        acc.z += __shfl_xor(acc.z, 32);
        acc.w += __shfl_xor(acc.w, 32);
        if (side == 0) {
            uint2 o;
            o.x = bf16rne(acc.x) | (bf16rne(acc.y) << 16);
            o.y = bf16rne(acc.z) | (bf16rne(acc.w) << 16);
            ((uint2*)agg16)[(size_t)node * 16 + p] = o;
        }
    }
}

// ---------------- 5. syrk from bf16 agg: G-partials + colsum partials ----------------
__global__ __launch_bounds__(256) void syrk_kernel(const unsigned short* __restrict__ agg16,
                                                   float* __restrict__ Gp)
{
    __shared__ float As[32][64];
    const int t = threadIdx.x, blk = blockIdx.x;
    const int row_beg = blk * SYRK_ROWS;
    int row_end = row_beg + SYRK_ROWS;
    if (row_end > N_NODES) row_end = N_NODES;

    const int i0 = (t & 15) * 4, j0 = (t >> 4) * 4;
    float acc[4][4];
#pragma unroll
    for (int i = 0; i < 4; i++)
#pragma unroll
        for (int j = 0; j < 4; j++) acc[i][j] = 0.f;
    float cs = 0.f;

    for (int r0 = row_beg; r0 < row_end; r0 += 32) {
        int nrows = row_end - r0; if (nrows > 32) nrows = 32;
        const uint2* g = (const uint2*)(agg16 + (size_t)r0 * IN_DIM);
        for (int i = t; i < nrows * 16; i += 256) {
            uint2 u = g[i];
            int row = i >> 4, c = (i & 15) * 4;
            As[row][c + 0] = bf16lo(u.x);
            As[row][c + 1] = bf16hi(u.x);
            As[row][c + 2] = bf16lo(u.y);
            As[row][c + 3] = bf16hi(u.y);
        }
        __syncthreads();
        for (int r = 0; r < nrows; ++r) {
            float4 ai = *(const float4*)&As[r][i0];
            float4 aj = *(const float4*)&As[r][j0];
            acc[0][0] += ai.x * aj.x; acc[0][1] += ai.x * aj.y;
            acc[0][2] += ai.x * aj.z; acc[0][3] += ai.x * aj.w;
            acc[1][0] += ai.y * aj.x; acc[1][1] += ai.y * aj.y;
            acc[1][2] += ai.y * aj.z; acc[1][3] += ai.y * aj.w;
            acc[2][0] += ai.z * aj.x; acc[2][1] += ai.z * aj.y;
            acc[2][2] += ai.z * aj.z; acc[2][3] += ai.z * aj.w;
            acc[3][0] += ai.w * aj.x; acc[3][1] += ai.w * aj.y;
            acc[3][2] += ai.w * aj.z; acc[3][3] += ai.w * aj.w;
        }
        if (t < 64) {
            for (int r = 0; r < nrows; ++r) cs += As[r][t];
        }
        __syncthreads();
    }
    float* gp = Gp + (size_t)blk * GSZ;
#pragma unroll
    for (int i = 0; i < 4; i++)
#pragma unroll
        for (int j = 0; j < 4; j++)
            gp[(i0 + i) * 64 + (j0 + j)] = acc[i][j];
    if (t < 64) gp[4096 + t] = cs;
}

// ---------------- 6. reduce G partials ----------------
__global__ __launch_bounds__(256) void reduceG_kernel(const float* __restrict__ Gp,
                                                      float* __restrict__ G)
{
    int gid = blockIdx.x * 256 + threadIdx.x;
    if (gid < GSZ) {
        float s = 0.f;
        for (int b = 0; b < SYRK_BLOCKS; ++b) s += Gp[(size_t)b * GSZ + gid];
        G[gid] = s;
    }
}

// ---------------- 7. finalize: per-column scale/shift from G ----------------
__global__ __launch_bounds__(256) void finalize_kernel(
    const float* __restrict__ G, const float* __restrict__ W,
    const float* __restrict__ bias, const float* __restrict__ gamma,
    const float* __restrict__ beta, float* __restrict__ scale,
    float* __restrict__ shift)
{
    __shared__ float Gs[4096];
    __shared__ float ss[64];
    __shared__ float part[256];
    const int t = threadIdx.x;
    for (int i = t; i < 4096; i += 256) Gs[i] = G[i];
    if (t < 64) ss[t] = G[4096 + t];
    __syncthreads();

    const int c = t & 127, half = t >> 7;
    float wc[64];
#pragma unroll
    for (int k = 0; k < 64; ++k) wc[k] = W[k * HID + c];

    float p = 0.f;
    for (int k1 = 0; k1 < 32; ++k1) {
        int k1g = half * 32 + k1;
        float dot = 0.f;
#pragma unroll
        for (int k2 = 0; k2 < 64; ++k2) dot += Gs[k1g * 64 + k2] * wc[k2];
        p += W[k1g * HID + c] * dot;
    }
    part[t] = p;
    __syncthreads();
    if (half == 0) {
        float quad = part[c] + part[c + 128];  // w_c^T G w_c
        float tc = 0.f;
#pragma unroll
        for (int k = 0; k < 64; ++k) tc += ss[k] * wc[k];
        const float invN = 1.0f / (float)N_NODES;
        float bc   = bias[c];
        float mean = tc * invN + bc;
        float ez2  = quad * invN + 2.f * bc * tc * invN + bc * bc;
        float var  = ez2 - mean * mean;
        float inv  = rsqrtf(var + BN_EPS);
        float scv  = gamma[c] * inv;
        scale[c] = scv;
        shift[c] = beta[c] - mean * scv;
    }
}

// ---------------- 8. GEMM from bf16 agg + scale/shift epilogue ----------------
#define AST_LD 36   // row stride of Ast in floats (16B-aligned, odd bank group)
__global__ __launch_bounds__(256) void gemm_out_kernel(
    const unsigned short* __restrict__ agg16, const float* __restrict__ W,
    const float* __restrict__ scale, const float* __restrict__ shift,
    float* __restrict__ out)
{
    __shared__ float Ws[IN_DIM][HID];        // 32 KB
    __shared__ float Ast[IN_DIM][AST_LD];    // 9 KB, Ast[k][row]
    const int t = threadIdx.x;
    const int tile = blockIdx.x;
    const int rowbase = tile * 32;

    {
        const float4* s4 = (const float4*)W;
        float4* d4 = (float4*)&Ws[0][0];
#pragma unroll
        for (int i = 0; i < (IN_DIM * HID / 4) / 256; ++i)
            d4[t + i * 256] = s4[t + i * 256];
    }
    {
        const uint2* g = (const uint2*)(agg16 + (size_t)rowbase * IN_DIM);
#pragma unroll
        for (int it = 0; it < 2; ++it) {
            int l = t + it * 256;
            uint2 u = g[l];
            int row = l >> 4, kg = (l & 15) * 4;
            Ast[kg + 0][row] = bf16lo(u.x);
            Ast[kg + 1][row] = bf16hi(u.x);
            Ast[kg + 2][row] = bf16lo(u.y);
            Ast[kg + 3][row] = bf16hi(u.y);
        }
    }
    __syncthreads();

    const int c4 = (t & 31) * 4;
    const int r0 = (t >> 5) * 4;

    float acc[4][4];
#pragma unroll
    for (int i = 0; i < 4; i++)
#pragma unroll
        for (int j = 0; j < 4; j++) acc[i][j] = 0.f;

#pragma unroll 8
    for (int k = 0; k < IN_DIM; ++k) {
        float4 w4 = *(const float4*)&Ws[k][c4];
        float4 a4 = *(const float4*)&Ast[k][r0];
        acc[0][0] += a4.x * w4.x; acc[0][1] += a4.x * w4.y;
        acc[0][2] += a4.x * w4.z; acc[0][3] += a4.x * w4.w;
        acc[1][0] += a4.y * w4.x; acc[1][1] += a4.y * w4.y;
        acc[1][2] += a4.y * w4.z; acc[1][3] += a4.y * w4.w;
        acc[2][0] += a4.z * w4.x; acc[2][1] += a4.z * w4.y;
        acc[2][2] += a4.z * w4.z; acc[2][3] += a4.z * w4.w;
        acc[3][0] += a4.w * w4.x; acc[3][1] += a4.w * w4.y;
        acc[3][2] += a4.w * w4.z; acc[3][3] += a4.w * w4.w;
    }

    const float4 sc4 = ((const float4*)scale)[t & 31];
    const float4 sh4 = ((const float4*)shift)[t & 31];
#pragma unroll
    for (int i = 0; i < 4; ++i) {
        float4 o;
        o.x = acc[i][0] * sc4.x + sh4.x;
        o.y = acc[i][1] * sc4.y + sh4.y;
        o.z = acc[i][2] * sc4.z + sh4.z;
        o.w = acc[i][3] * sc4.w + sh4.w;
        *(float4*)&out[(size_t)(rowbase + r0 + i) * HID + c4] = o;
    }
}

extern "C" void kernel_launch(void* const* d_in, const int* in_sizes, int n_in,
                              void* d_out, int out_size, void* d_ws, size_t ws_size,
                              hipStream_t stream)
{
    const float* h     = (const float*)d_in[0];
    const int*   src   = (const int*)d_in[1];
    const int*   dst   = (const int*)d_in[2];
    const float* W     = (const float*)d_in[3];
    const float* b     = (const float*)d_in[4];
    const float* gamma = (const float*)d_in[5];
    const float* beta  = (const float*)d_in[6];

    float* out = (float*)d_out;

    // ---- workspace layout ----
    // persistent: agg16 (12.8 MB) | h16 (12.8 MB) | G | scale | shift
    unsigned short* agg16 = (unsigned short*)d_ws;
    unsigned short* h16   = agg16 + (size_t)N_NODES * IN_DIM;
    float* G     = (float*)(h16 + (size_t)N_NODES * IN_DIM);
    float* scale = G + GSZ;
    float* shift = scale + HID;
    // transient: counts | blockSums | scanned | packed (~7.7 MB); Gp aliases it post-sort
    int*  counts    = (int*)(shift + HID);
    int*  blockSums = counts + SC_PAD;
    int*  scanned   = blockSums + 256;
    int*  packed    = scanned + SC_PAD;          // N_EDGES ints
    float* Gp       = (float*)counts;            // aliases sort transients (dead by syrk)

    count_conv_kernel<<<BC_BLOCKS + CONV_BLOCKS + 1, 256, 0, stream>>>(dst, counts,
                                                                       h, h16);
    scanA_kernel<<<SC_NBLK, 256, 0, stream>>>(counts, blockSums);
    scanC_kernel<<<SC_NBLK, 256, 0, stream>>>(counts, blockSums, scanned);
    binPlace_kernel<<<BC_BLOCKS, 256, 0, stream>>>(src, dst, scanned, packed);
    sortAgg_kernel<<<NB, 512, 0, stream>>>((const uint2*)h16, packed, scanned, agg16);
    syrk_kernel<<<SYRK_BLOCKS, 256, 0, stream>>>(agg16, Gp);
    reduceG_kernel<<<(GSZ + 255) / 256, 256, 0, stream>>>(Gp, G);
    finalize_kernel<<<1, 256, 0, stream>>>(G, W, b, gamma, beta, scale, shift);
    gemm_out_kernel<<<N_NODES / 32, 256, 0, stream>>>(agg16, W, scale, shift, out);
}